// Round 12
// baseline (431.804 us; speedup 1.0000x reference)
//
#include <hip/hip_runtime.h>
#include <math.h>

#define NNODE 50000
#define NEDGE 800000
#define NBLK 196   // ceil(50000/256)

__device__ __forceinline__ float wsum64(float v) {
    #pragma unroll
    for (int m = 32; m >= 1; m >>= 1) v += __shfl_xor(v, m, 64);
    return v;
}

__device__ __forceinline__ float gelu_exact(float x) {
    return 0.5f * x * (1.0f + erff(x * 0.70710678118654752f));
}

__device__ __forceinline__ float lrelu(float z) { return z > 0.f ? z : 0.2f * z; }

// ---------------- utility ----------------
__global__ void fill_u32(unsigned* __restrict__ p, unsigned v, int n) {
    int i = blockIdx.x * blockDim.x + threadIdx.x;
    if (i < n) p[i] = v;
}

// ---------------- CSR build ----------------
__global__ __launch_bounds__(256) void build_deg(const int* __restrict__ ei, int* __restrict__ deg) {
    int e = blockIdx.x * 256 + threadIdx.x;
    if (e >= NEDGE) return;
    atomicAdd(&deg[ei[NEDGE + e]], 1);
}

// three-phase parallel exclusive scan
__global__ __launch_bounds__(256) void scan1(const int* __restrict__ deg,
                                             int* __restrict__ partial,
                                             int* __restrict__ bsum) {
    __shared__ int tmp[256];
    int t = threadIdx.x;
    int gid = blockIdx.x * 256 + t;
    int v = (gid < NNODE) ? deg[gid] : 0;
    tmp[t] = v;
    __syncthreads();
    #pragma unroll
    for (int off = 1; off < 256; off <<= 1) {
        int u = (t >= off) ? tmp[t - off] : 0;
        __syncthreads();
        tmp[t] += u;
        __syncthreads();
    }
    if (gid < NNODE) partial[gid] = tmp[t] - v;   // exclusive
    if (t == 255) bsum[blockIdx.x] = tmp[255];
}

__global__ __launch_bounds__(256) void scan2(int* __restrict__ bsum, int* __restrict__ boff) {
    __shared__ int tmp[256];
    int t = threadIdx.x;
    int v = (t < NBLK) ? bsum[t] : 0;
    tmp[t] = v;
    __syncthreads();
    #pragma unroll
    for (int off = 1; off < 256; off <<= 1) {
        int u = (t >= off) ? tmp[t - off] : 0;
        __syncthreads();
        tmp[t] += u;
        __syncthreads();
    }
    if (t < NBLK) boff[t] = tmp[t] - v;      // exclusive
}

__global__ __launch_bounds__(256) void scan3(const int* __restrict__ partial,
                                             const int* __restrict__ boff,
                                             int* __restrict__ base,
                                             int* __restrict__ cursor) {
    int gid = blockIdx.x * 256 + threadIdx.x;
    if (gid < NNODE) {
        int b = partial[gid] + boff[blockIdx.x];
        base[gid] = b;
        cursor[gid] = b;
    }
    if (gid == 0) base[NNODE] = NEDGE;
}

__global__ __launch_bounds__(256) void scatter_edges(const int* __restrict__ ei,
                                                     const float* __restrict__ ea,
                                                     int* __restrict__ cursor,
                                                     int2* __restrict__ se) {
    int e = blockIdx.x * 256 + threadIdx.x;
    if (e >= NEDGE) return;
    int d = ei[NEDGE + e];
    int i = atomicAdd(&cursor[d], 1);
    se[i] = make_int2(ei[e], __float_as_int(ea[e]));
}

// ---------------- node transform: 32 nodes/block, thread owns 4 cols x 8 nodes ----------
template<int K>
__global__ __launch_bounds__(256) void node_xform(const float* __restrict__ in,
                                                  const float* __restrict__ wl,
                                                  const float* __restrict__ wr,
                                                  float* __restrict__ xl,
                                                  float* __restrict__ xr) {
    __shared__ float xrow[32][K];
    int t = threadIdx.x;
    int n0 = blockIdx.x * 32;
    for (int idx = t; idx < 32 * (K / 4); idx += 256) {
        int row = idx / (K / 4), c4 = idx % (K / 4);
        float4 v = make_float4(0.f, 0.f, 0.f, 0.f);
        if (n0 + row < NNODE) v = ((const float4*)(in + (size_t)(n0 + row) * K))[c4];
        ((float4*)xrow[row])[c4] = v;
    }
    __syncthreads();
    int cg = t & 63, ns = t >> 6;
    const float* wsel = (cg < 32) ? wl : wr;
    float* osel = (cg < 32) ? xl : xr;
    int ccol = (cg & 31) * 4;
    const float* wp = wsel + ccol;
    const float* xbase = xrow[ns * 8];
    float4 acc[8];
    #pragma unroll
    for (int k = 0; k < 8; ++k) acc[k] = make_float4(0.f, 0.f, 0.f, 0.f);
    for (int i = 0; i < K; i += 4) {
        float4 w0 = *(const float4*)(wp + (size_t)(i + 0) * 128);
        float4 w1 = *(const float4*)(wp + (size_t)(i + 1) * 128);
        float4 w2 = *(const float4*)(wp + (size_t)(i + 2) * 128);
        float4 w3 = *(const float4*)(wp + (size_t)(i + 3) * 128);
        #pragma unroll
        for (int k = 0; k < 8; ++k) {
            float4 xv = *(const float4*)(xbase + (size_t)k * K + i);
            acc[k].x += xv.x * w0.x + xv.y * w1.x + xv.z * w2.x + xv.w * w3.x;
            acc[k].y += xv.x * w0.y + xv.y * w1.y + xv.z * w2.y + xv.w * w3.y;
            acc[k].z += xv.x * w0.z + xv.y * w1.z + xv.z * w2.z + xv.w * w3.z;
            acc[k].w += xv.x * w0.w + xv.y * w1.w + xv.z * w2.w + xv.w * w3.w;
        }
    }
    #pragma unroll
    for (int k = 0; k < 8; ++k) {
        int n = n0 + ns * 8 + k;
        if (n < NNODE) *(float4*)(osel + (size_t)n * 128 + ccol) = acc[k];
    }
}

// ---------------- fused online-softmax GAT layer 1 (H=8, C=16) ----------------
__global__ __launch_bounds__(256) void fused1(const int* __restrict__ base,
                                              const int2* __restrict__ se,
                                              const float* __restrict__ xl,
                                              const float* __restrict__ xr,
                                              const float* __restrict__ w1e,
                                              const float* __restrict__ att1,
                                              const float* __restrict__ b1,
                                              float* __restrict__ h1) {
    int t = threadIdx.x;
    int wv = t >> 6, ln = t & 63;
    int half = ln >> 5, sub = ln & 31;
    int n = blockIdx.x * 4 + wv;
    int ch = sub * 4;
    float4 xrv = *(const float4*)(xr + (size_t)n * 128 + ch);
    float4 wev = *(const float4*)(w1e + ch);
    float4 atv = *(const float4*)(att1 + ch);
    int i0 = base[n], i1 = base[n + 1];
    float m = -1e30f, den = 0.f;
    float4 o = make_float4(0.f, 0.f, 0.f, 0.f);
    int i = i0 + half;
    if (i < i1) {
        int2 r = se[i];
        float4 xv = *(const float4*)(xl + (size_t)r.x * 128 + ch);
        float a = __int_as_float(r.y);
        for (i += 2; i < i1; i += 2) {
            int2 rn = se[i];
            float4 nxv = *(const float4*)(xl + (size_t)rn.x * 128 + ch);
            float na = __int_as_float(rn.y);
            float part = lrelu(fmaf(a, wev.x, xv.x + xrv.x)) * atv.x
                       + lrelu(fmaf(a, wev.y, xv.y + xrv.y)) * atv.y
                       + lrelu(fmaf(a, wev.z, xv.z + xrv.z)) * atv.z
                       + lrelu(fmaf(a, wev.w, xv.w + xrv.w)) * atv.w;
            part += __shfl_xor(part, 1, 64);
            part += __shfl_xor(part, 2, 64);
            float mn = fmaxf(m, part);
            float sc = __expf(m - mn);
            float p  = __expf(part - mn);
            den = den * sc + p;
            o.x = o.x * sc + p * xv.x;
            o.y = o.y * sc + p * xv.y;
            o.z = o.z * sc + p * xv.z;
            o.w = o.w * sc + p * xv.w;
            m = mn;
            xv = nxv; a = na;
        }
        float part = lrelu(fmaf(a, wev.x, xv.x + xrv.x)) * atv.x
                   + lrelu(fmaf(a, wev.y, xv.y + xrv.y)) * atv.y
                   + lrelu(fmaf(a, wev.z, xv.z + xrv.z)) * atv.z
                   + lrelu(fmaf(a, wev.w, xv.w + xrv.w)) * atv.w;
        part += __shfl_xor(part, 1, 64);
        part += __shfl_xor(part, 2, 64);
        float mn = fmaxf(m, part);
        float sc = __expf(m - mn);
        float p  = __expf(part - mn);
        den = den * sc + p;
        o.x = o.x * sc + p * xv.x;
        o.y = o.y * sc + p * xv.y;
        o.z = o.z * sc + p * xv.z;
        o.w = o.w * sc + p * xv.w;
        m = mn;
    }
    float m2   = __shfl_xor(m, 32, 64);
    float den2 = __shfl_xor(den, 32, 64);
    float4 o2;
    o2.x = __shfl_xor(o.x, 32, 64);
    o2.y = __shfl_xor(o.y, 32, 64);
    o2.z = __shfl_xor(o.z, 32, 64);
    o2.w = __shfl_xor(o.w, 32, 64);
    float mn = fmaxf(m, m2);
    float s1 = __expf(m - mn), s2 = __expf(m2 - mn);
    den = den * s1 + den2 * s2;
    float inv = 1.f / (den + 1e-16f);
    if (half == 0) {
        float4 bv = *(const float4*)(b1 + ch);
        float4 res;
        res.x = fmaxf((o.x * s1 + o2.x * s2) * inv + bv.x, 0.f);
        res.y = fmaxf((o.y * s1 + o2.y * s2) * inv + bv.y, 0.f);
        res.z = fmaxf((o.z * s1 + o2.z * s2) * inv + bv.z, 0.f);
        res.w = fmaxf((o.w * s1 + o2.w * s2) * inv + bv.w, 0.f);
        *(float4*)(h1 + (size_t)n * 128 + ch) = res;
    }
}

// ---------------- fused online-softmax GAT layer 2 (H=2, C=64, mean) ----------------
__global__ __launch_bounds__(256) void fused2(const int* __restrict__ base,
                                              const int2* __restrict__ se,
                                              const float* __restrict__ xl,
                                              const float* __restrict__ xr,
                                              const float* __restrict__ w2e,
                                              const float* __restrict__ att2,
                                              const float* __restrict__ b2,
                                              float* __restrict__ h2) {
    int t = threadIdx.x;
    int wv = t >> 6, ln = t & 63;
    int half = ln >> 5, sub = ln & 31;
    int n = blockIdx.x * 4 + wv;
    int ch = sub * 4;
    float4 xrv = *(const float4*)(xr + (size_t)n * 128 + ch);
    float4 wev = *(const float4*)(w2e + ch);
    float4 atv = *(const float4*)(att2 + ch);
    int i0 = base[n], i1 = base[n + 1];
    float m = -1e30f, den = 0.f;
    float4 o = make_float4(0.f, 0.f, 0.f, 0.f);
    int i = i0 + half;
    if (i < i1) {
        int2 r = se[i];
        float4 xv = *(const float4*)(xl + (size_t)r.x * 128 + ch);
        float a = __int_as_float(r.y);
        for (i += 2; i < i1; i += 2) {
            int2 rn = se[i];
            float4 nxv = *(const float4*)(xl + (size_t)rn.x * 128 + ch);
            float na = __int_as_float(rn.y);
            float part = lrelu(fmaf(a, wev.x, xv.x + xrv.x)) * atv.x
                       + lrelu(fmaf(a, wev.y, xv.y + xrv.y)) * atv.y
                       + lrelu(fmaf(a, wev.z, xv.z + xrv.z)) * atv.z
                       + lrelu(fmaf(a, wev.w, xv.w + xrv.w)) * atv.w;
            part += __shfl_xor(part, 1, 64);
            part += __shfl_xor(part, 2, 64);
            part += __shfl_xor(part, 4, 64);
            part += __shfl_xor(part, 8, 64);
            float mn = fmaxf(m, part);
            float sc = __expf(m - mn);
            float p  = __expf(part - mn);
            den = den * sc + p;
            o.x = o.x * sc + p * xv.x;
            o.y = o.y * sc + p * xv.y;
            o.z = o.z * sc + p * xv.z;
            o.w = o.w * sc + p * xv.w;
            m = mn;
            xv = nxv; a = na;
        }
        float part = lrelu(fmaf(a, wev.x, xv.x + xrv.x)) * atv.x
                   + lrelu(fmaf(a, wev.y, xv.y + xrv.y)) * atv.y
                   + lrelu(fmaf(a, wev.z, xv.z + xrv.z)) * atv.z
                   + lrelu(fmaf(a, wev.w, xv.w + xrv.w)) * atv.w;
        part += __shfl_xor(part, 1, 64);
        part += __shfl_xor(part, 2, 64);
        part += __shfl_xor(part, 4, 64);
        part += __shfl_xor(part, 8, 64);
        float mn = fmaxf(m, part);
        float sc = __expf(m - mn);
        float p  = __expf(part - mn);
        den = den * sc + p;
        o.x = o.x * sc + p * xv.x;
        o.y = o.y * sc + p * xv.y;
        o.z = o.z * sc + p * xv.z;
        o.w = o.w * sc + p * xv.w;
        m = mn;
    }
    float m2   = __shfl_xor(m, 32, 64);
    float den2 = __shfl_xor(den, 32, 64);
    float4 o2;
    o2.x = __shfl_xor(o.x, 32, 64);
    o2.y = __shfl_xor(o.y, 32, 64);
    o2.z = __shfl_xor(o.z, 32, 64);
    o2.w = __shfl_xor(o.w, 32, 64);
    float mn = fmaxf(m, m2);
    float s1 = __expf(m - mn), s2 = __expf(m2 - mn);
    den = den * s1 + den2 * s2;
    float inv = 1.f / (den + 1e-16f);
    float4 v;
    v.x = (o.x * s1 + o2.x * s2) * inv;
    v.y = (o.y * s1 + o2.y * s2) * inv;
    v.z = (o.z * s1 + o2.z * s2) * inv;
    v.w = (o.w * s1 + o2.w * s2) * inv;
    float4 u;
    u.x = __shfl_xor(v.x, 16, 64);
    u.y = __shfl_xor(v.y, 16, 64);
    u.z = __shfl_xor(v.z, 16, 64);
    u.w = __shfl_xor(v.w, 16, 64);
    if (half == 0 && sub < 16) {
        float4 bv = *(const float4*)(b2 + ch);
        float4 res;
        res.x = fmaxf(0.5f * (v.x + u.x) + bv.x, 0.f);
        res.y = fmaxf(0.5f * (v.y + u.y) + bv.y, 0.f);
        res.z = fmaxf(0.5f * (v.z + u.z) + bv.z, 0.f);
        res.w = fmaxf(0.5f * (v.w + u.w) + bv.w, 0.f);
        *(float4*)(h2 + (size_t)n * 64 + ch) = res;
    }
}

// ------- classifier v3: 64 nodes/block, 4 cols x 4 nodes per thread, ------------
// LN computed IN REGISTERS with one 4-step 16-lane-group reduce (no serial phases)
__global__ __launch_bounds__(256) void classifier(const float* __restrict__ h2,
                                                  const float* __restrict__ wc,
                                                  const float* __restrict__ bc,
                                                  const float* __restrict__ lng,
                                                  const float* __restrict__ lnb,
                                                  const float* __restrict__ wrr,
                                                  const float* __restrict__ brr,
                                                  const float* __restrict__ lrg,
                                                  const float* __restrict__ lrb,
                                                  float* __restrict__ out) {
    __shared__ float sA[64][68];    // h2 rows, later overwritten with g1 rows
    int t = threadIdx.x;
    int n0 = blockIdx.x * 64;
    for (int idx = t; idx < 64 * 16; idx += 256) {
        int row = idx >> 4, c4 = idx & 15;
        float4 v = make_float4(0.f, 0.f, 0.f, 0.f);
        if (n0 + row < NNODE) v = ((const float4*)(h2 + (size_t)(n0 + row) * 64))[c4];
        *(float4*)(&sA[row][c4 * 4]) = v;
    }
    __syncthreads();
    int cg = t & 15, ng = t >> 4;        // 4 cols x 4 nodes per thread
    int ccol = cg * 4;
    float4 lngv = *(const float4*)(lng + ccol);
    float4 lnbv = *(const float4*)(lnb + ccol);
    float4 lrgv = *(const float4*)(lrg + ccol);
    float4 lrbv = *(const float4*)(lrb + ccol);
    float4 g1r[4];
    // ---- matvec1 + LN1 + GELU (all in registers) ----
    {
        float4 bv = *(const float4*)(bc + ccol);
        float4 acc[4];
        #pragma unroll
        for (int k = 0; k < 4; ++k) acc[k] = bv;
        for (int i = 0; i < 64; i += 4) {
            float4 w0 = *(const float4*)(wc + (size_t)(i + 0) * 64 + ccol);
            float4 w1 = *(const float4*)(wc + (size_t)(i + 1) * 64 + ccol);
            float4 w2 = *(const float4*)(wc + (size_t)(i + 2) * 64 + ccol);
            float4 w3 = *(const float4*)(wc + (size_t)(i + 3) * 64 + ccol);
            #pragma unroll
            for (int k = 0; k < 4; ++k) {
                float4 hv = *(const float4*)(&sA[ng * 4 + k][i]);
                acc[k].x += hv.x * w0.x + hv.y * w1.x + hv.z * w2.x + hv.w * w3.x;
                acc[k].y += hv.x * w0.y + hv.y * w1.y + hv.z * w2.y + hv.w * w3.y;
                acc[k].z += hv.x * w0.z + hv.y * w1.z + hv.z * w2.z + hv.w * w3.z;
                acc[k].w += hv.x * w0.w + hv.y * w1.w + hv.z * w2.w + hv.w * w3.w;
            }
        }
        #pragma unroll
        for (int k = 0; k < 4; ++k) {
            float ssum = acc[k].x + acc[k].y + acc[k].z + acc[k].w;
            float ssq  = acc[k].x * acc[k].x + acc[k].y * acc[k].y
                       + acc[k].z * acc[k].z + acc[k].w * acc[k].w;
            #pragma unroll
            for (int d = 1; d < 16; d <<= 1) {
                ssum += __shfl_xor(ssum, d, 64);
                ssq  += __shfl_xor(ssq, d, 64);
            }
            float mu = ssum * (1.f / 64.f);
            float var = ssq * (1.f / 64.f) - mu * mu;
            float rstd = rsqrtf(var + 1e-5f);
            g1r[k].x = gelu_exact((acc[k].x - mu) * rstd * lngv.x + lnbv.x);
            g1r[k].y = gelu_exact((acc[k].y - mu) * rstd * lngv.y + lnbv.y);
            g1r[k].z = gelu_exact((acc[k].z - mu) * rstd * lngv.z + lnbv.z);
            g1r[k].w = gelu_exact((acc[k].w - mu) * rstd * lngv.w + lnbv.w);
        }
    }
    __syncthreads();   // all matvec1 reads of sA complete
    #pragma unroll
    for (int k = 0; k < 4; ++k) *(float4*)(&sA[ng * 4 + k][ccol]) = g1r[k];
    __syncthreads();
    // ---- matvec2 + LN2 + GELU + residual ----
    {
        float4 bv = *(const float4*)(brr + ccol);
        float4 acc[4];
        #pragma unroll
        for (int k = 0; k < 4; ++k) acc[k] = bv;
        for (int i = 0; i < 64; i += 4) {
            float4 w0 = *(const float4*)(wrr + (size_t)(i + 0) * 64 + ccol);
            float4 w1 = *(const float4*)(wrr + (size_t)(i + 1) * 64 + ccol);
            float4 w2 = *(const float4*)(wrr + (size_t)(i + 2) * 64 + ccol);
            float4 w3 = *(const float4*)(wrr + (size_t)(i + 3) * 64 + ccol);
            #pragma unroll
            for (int k = 0; k < 4; ++k) {
                float4 hv = *(const float4*)(&sA[ng * 4 + k][i]);
                acc[k].x += hv.x * w0.x + hv.y * w1.x + hv.z * w2.x + hv.w * w3.x;
                acc[k].y += hv.x * w0.y + hv.y * w1.y + hv.z * w2.y + hv.w * w3.y;
                acc[k].z += hv.x * w0.z + hv.y * w1.z + hv.z * w2.z + hv.w * w3.z;
                acc[k].w += hv.x * w0.w + hv.y * w1.w + hv.z * w2.w + hv.w * w3.w;
            }
        }
        #pragma unroll
        for (int k = 0; k < 4; ++k) {
            float ssum = acc[k].x + acc[k].y + acc[k].z + acc[k].w;
            float ssq  = acc[k].x * acc[k].x + acc[k].y * acc[k].y
                       + acc[k].z * acc[k].z + acc[k].w * acc[k].w;
            #pragma unroll
            for (int d = 1; d < 16; d <<= 1) {
                ssum += __shfl_xor(ssum, d, 64);
                ssq  += __shfl_xor(ssq, d, 64);
            }
            float mu = ssum * (1.f / 64.f);
            float var = ssq * (1.f / 64.f) - mu * mu;
            float rstd = rsqrtf(var + 1e-5f);
            float4 res;
            res.x = g1r[k].x + gelu_exact((acc[k].x - mu) * rstd * lrgv.x + lrbv.x);
            res.y = g1r[k].y + gelu_exact((acc[k].y - mu) * rstd * lrgv.y + lrbv.y);
            res.z = g1r[k].z + gelu_exact((acc[k].z - mu) * rstd * lrgv.z + lrbv.z);
            res.w = g1r[k].w + gelu_exact((acc[k].w - mu) * rstd * lrgv.w + lrbv.w);
            int n = n0 + ng * 4 + k;
            if (n < NNODE) *(float4*)(out + (size_t)n * 64 + ccol) = res;
        }
    }
}

extern "C" void kernel_launch(void* const* d_in, const int* in_sizes, int n_in,
                              void* d_out, int out_size, void* d_ws, size_t ws_size,
                              hipStream_t stream) {
    const float* x    = (const float*)d_in[0];
    const int*   ei   = (const int*)d_in[1];
    const float* ea   = (const float*)d_in[2];
    const float* w1l  = (const float*)d_in[3];
    const float* w1r  = (const float*)d_in[4];
    const float* w1e  = (const float*)d_in[5];
    const float* att1 = (const float*)d_in[6];
    const float* b1   = (const float*)d_in[7];
    const float* w2l  = (const float*)d_in[8];
    const float* w2r  = (const float*)d_in[9];
    const float* w2e  = (const float*)d_in[10];
    const float* att2 = (const float*)d_in[11];
    const float* b2   = (const float*)d_in[12];
    const float* wc   = (const float*)d_in[13];
    const float* bc   = (const float*)d_in[14];
    const float* lng  = (const float*)d_in[15];
    const float* lnb  = (const float*)d_in[16];
    const float* wr   = (const float*)d_in[17];
    const float* br   = (const float*)d_in[18];
    const float* lrg  = (const float*)d_in[19];
    const float* lrb  = (const float*)d_in[20];

    float* ws = (float*)d_ws;
    const size_t N128 = (size_t)NNODE * 128;
    float* xl = ws;
    float* xr = xl + N128;
    float* h1 = xr + N128;
    float* h2 = h1 + N128;                    // N*64
    int2*  se      = (int2*)(h2 + (size_t)NNODE * 64);   // NEDGE (8B aligned)
    int*   deg     = (int*)(se + NEDGE);
    int*   partial = deg + NNODE;
    int*   base    = partial + NNODE;         // NNODE+1
    int*   cursor  = base + NNODE + 1;
    int*   bsum    = cursor + NNODE;          // 256
    int*   boff    = bsum + 256;              // 256

    const int EB  = NEDGE / 256;              // 3125
    const int NBX = (NNODE + 31) / 32;        // 1563
    const int NB4 = NNODE / 4;                // 12500
    const int NBC = (NNODE + 63) / 64;        // 782

    // ---- CSR build (dst-sorted) ----
    fill_u32<<<NBLK, 256, 0, stream>>>((unsigned*)deg, 0u, NNODE);
    build_deg<<<EB, 256, 0, stream>>>(ei, deg);
    scan1<<<NBLK, 256, 0, stream>>>(deg, partial, bsum);
    scan2<<<1, 256, 0, stream>>>(bsum, boff);
    scan3<<<NBLK, 256, 0, stream>>>(partial, boff, base, cursor);
    scatter_edges<<<EB, 256, 0, stream>>>(ei, ea, cursor, se);

    // ---- layer 1 ----
    node_xform<64><<<NBX, 256, 0, stream>>>(x, w1l, w1r, xl, xr);
    fused1<<<NB4, 256, 0, stream>>>(base, se, xl, xr, w1e, att1, b1, h1);

    // ---- layer 2 ----
    node_xform<128><<<NBX, 256, 0, stream>>>(h1, w2l, w2r, xl, xr);
    fused2<<<NB4, 256, 0, stream>>>(base, se, xl, xr, w2e, att2, b2, h2);

    // ---- classifier (reg-blocked GEMM + in-register LN) ----
    classifier<<<NBC, 256, 0, stream>>>(h2, wc, bc, lng, lnb, wr, br, lrg, lrb,
                                        (float*)d_out);
}

// Round 13
// 349.334 us; speedup vs baseline: 1.2361x; 1.2361x over previous
//
#include <hip/hip_runtime.h>
#include <math.h>

#define NNODE 50000
#define NEDGE 800000
#define NBLK 196   // ceil(50000/256)

__device__ __forceinline__ float gelu_exact(float x) {
    return 0.5f * x * (1.0f + erff(x * 0.70710678118654752f));
}

__device__ __forceinline__ float lrelu(float z) { return z > 0.f ? z : 0.2f * z; }

// ---------------- utility ----------------
__global__ void fill_u32(unsigned* __restrict__ p, unsigned v, int n) {
    int i = blockIdx.x * blockDim.x + threadIdx.x;
    if (i < n) p[i] = v;
}

// ---------------- CSR build ----------------
__global__ __launch_bounds__(256) void build_deg(const int* __restrict__ ei, int* __restrict__ deg) {
    int e = blockIdx.x * 256 + threadIdx.x;
    if (e >= NEDGE) return;
    atomicAdd(&deg[ei[NEDGE + e]], 1);
}

// three-phase parallel exclusive scan
__global__ __launch_bounds__(256) void scan1(const int* __restrict__ deg,
                                             int* __restrict__ partial,
                                             int* __restrict__ bsum) {
    __shared__ int tmp[256];
    int t = threadIdx.x;
    int gid = blockIdx.x * 256 + t;
    int v = (gid < NNODE) ? deg[gid] : 0;
    tmp[t] = v;
    __syncthreads();
    #pragma unroll
    for (int off = 1; off < 256; off <<= 1) {
        int u = (t >= off) ? tmp[t - off] : 0;
        __syncthreads();
        tmp[t] += u;
        __syncthreads();
    }
    if (gid < NNODE) partial[gid] = tmp[t] - v;   // exclusive
    if (t == 255) bsum[blockIdx.x] = tmp[255];
}

__global__ __launch_bounds__(256) void scan2(int* __restrict__ bsum, int* __restrict__ boff) {
    __shared__ int tmp[256];
    int t = threadIdx.x;
    int v = (t < NBLK) ? bsum[t] : 0;
    tmp[t] = v;
    __syncthreads();
    #pragma unroll
    for (int off = 1; off < 256; off <<= 1) {
        int u = (t >= off) ? tmp[t - off] : 0;
        __syncthreads();
        tmp[t] += u;
        __syncthreads();
    }
    if (t < NBLK) boff[t] = tmp[t] - v;      // exclusive
}

__global__ __launch_bounds__(256) void scan3(const int* __restrict__ partial,
                                             const int* __restrict__ boff,
                                             int* __restrict__ base,
                                             int* __restrict__ cursor) {
    int gid = blockIdx.x * 256 + threadIdx.x;
    if (gid < NNODE) {
        int b = partial[gid] + boff[blockIdx.x];
        base[gid] = b;
        cursor[gid] = b;
    }
    if (gid == 0) base[NNODE] = NEDGE;
}

__global__ __launch_bounds__(256) void scatter_edges(const int* __restrict__ ei,
                                                     const float* __restrict__ ea,
                                                     int* __restrict__ cursor,
                                                     int2* __restrict__ se) {
    int e = blockIdx.x * 256 + threadIdx.x;
    if (e >= NEDGE) return;
    int d = ei[NEDGE + e];
    int i = atomicAdd(&cursor[d], 1);
    se[i] = make_int2(ei[e], __float_as_int(ea[e]));
}

// ---------------- node transform: 32 nodes/block, thread owns 4 cols x 8 nodes ----------
template<int K>
__global__ __launch_bounds__(256) void node_xform(const float* __restrict__ in,
                                                  const float* __restrict__ wl,
                                                  const float* __restrict__ wr,
                                                  float* __restrict__ xl,
                                                  float* __restrict__ xr) {
    __shared__ float xrow[32][K];
    int t = threadIdx.x;
    int n0 = blockIdx.x * 32;
    for (int idx = t; idx < 32 * (K / 4); idx += 256) {
        int row = idx / (K / 4), c4 = idx % (K / 4);
        float4 v = make_float4(0.f, 0.f, 0.f, 0.f);
        if (n0 + row < NNODE) v = ((const float4*)(in + (size_t)(n0 + row) * K))[c4];
        ((float4*)xrow[row])[c4] = v;
    }
    __syncthreads();
    int cg = t & 63, ns = t >> 6;
    const float* wsel = (cg < 32) ? wl : wr;
    float* osel = (cg < 32) ? xl : xr;
    int ccol = (cg & 31) * 4;
    const float* wp = wsel + ccol;
    const float* xbase = xrow[ns * 8];
    float4 acc[8];
    #pragma unroll
    for (int k = 0; k < 8; ++k) acc[k] = make_float4(0.f, 0.f, 0.f, 0.f);
    for (int i = 0; i < K; i += 4) {
        float4 w0 = *(const float4*)(wp + (size_t)(i + 0) * 128);
        float4 w1 = *(const float4*)(wp + (size_t)(i + 1) * 128);
        float4 w2 = *(const float4*)(wp + (size_t)(i + 2) * 128);
        float4 w3 = *(const float4*)(wp + (size_t)(i + 3) * 128);
        #pragma unroll
        for (int k = 0; k < 8; ++k) {
            float4 xv = *(const float4*)(xbase + (size_t)k * K + i);
            acc[k].x += xv.x * w0.x + xv.y * w1.x + xv.z * w2.x + xv.w * w3.x;
            acc[k].y += xv.x * w0.y + xv.y * w1.y + xv.z * w2.y + xv.w * w3.y;
            acc[k].z += xv.x * w0.z + xv.y * w1.z + xv.z * w2.z + xv.w * w3.z;
            acc[k].w += xv.x * w0.w + xv.y * w1.w + xv.z * w2.w + xv.w * w3.w;
        }
    }
    #pragma unroll
    for (int k = 0; k < 8; ++k) {
        int n = n0 + ns * 8 + k;
        if (n < NNODE) *(float4*)(osel + (size_t)n * 128 + ccol) = acc[k];
    }
}

// ---------------- fused online-softmax GAT layer 1 (H=8, C=16) ----------------
__global__ __launch_bounds__(256) void fused1(const int* __restrict__ base,
                                              const int2* __restrict__ se,
                                              const float* __restrict__ xl,
                                              const float* __restrict__ xr,
                                              const float* __restrict__ w1e,
                                              const float* __restrict__ att1,
                                              const float* __restrict__ b1,
                                              float* __restrict__ h1) {
    int t = threadIdx.x;
    int wv = t >> 6, ln = t & 63;
    int half = ln >> 5, sub = ln & 31;
    int n = blockIdx.x * 4 + wv;
    int ch = sub * 4;
    float4 xrv = *(const float4*)(xr + (size_t)n * 128 + ch);
    float4 wev = *(const float4*)(w1e + ch);
    float4 atv = *(const float4*)(att1 + ch);
    int i0 = base[n], i1 = base[n + 1];
    float m = -1e30f, den = 0.f;
    float4 o = make_float4(0.f, 0.f, 0.f, 0.f);
    int i = i0 + half;
    if (i < i1) {
        int2 r = se[i];
        float4 xv = *(const float4*)(xl + (size_t)r.x * 128 + ch);
        float a = __int_as_float(r.y);
        for (i += 2; i < i1; i += 2) {
            int2 rn = se[i];
            float4 nxv = *(const float4*)(xl + (size_t)rn.x * 128 + ch);
            float na = __int_as_float(rn.y);
            float part = lrelu(fmaf(a, wev.x, xv.x + xrv.x)) * atv.x
                       + lrelu(fmaf(a, wev.y, xv.y + xrv.y)) * atv.y
                       + lrelu(fmaf(a, wev.z, xv.z + xrv.z)) * atv.z
                       + lrelu(fmaf(a, wev.w, xv.w + xrv.w)) * atv.w;
            part += __shfl_xor(part, 1, 64);
            part += __shfl_xor(part, 2, 64);
            float mn = fmaxf(m, part);
            float sc = __expf(m - mn);
            float p  = __expf(part - mn);
            den = den * sc + p;
            o.x = o.x * sc + p * xv.x;
            o.y = o.y * sc + p * xv.y;
            o.z = o.z * sc + p * xv.z;
            o.w = o.w * sc + p * xv.w;
            m = mn;
            xv = nxv; a = na;
        }
        float part = lrelu(fmaf(a, wev.x, xv.x + xrv.x)) * atv.x
                   + lrelu(fmaf(a, wev.y, xv.y + xrv.y)) * atv.y
                   + lrelu(fmaf(a, wev.z, xv.z + xrv.z)) * atv.z
                   + lrelu(fmaf(a, wev.w, xv.w + xrv.w)) * atv.w;
        part += __shfl_xor(part, 1, 64);
        part += __shfl_xor(part, 2, 64);
        float mn = fmaxf(m, part);
        float sc = __expf(m - mn);
        float p  = __expf(part - mn);
        den = den * sc + p;
        o.x = o.x * sc + p * xv.x;
        o.y = o.y * sc + p * xv.y;
        o.z = o.z * sc + p * xv.z;
        o.w = o.w * sc + p * xv.w;
        m = mn;
    }
    float m2   = __shfl_xor(m, 32, 64);
    float den2 = __shfl_xor(den, 32, 64);
    float4 o2;
    o2.x = __shfl_xor(o.x, 32, 64);
    o2.y = __shfl_xor(o.y, 32, 64);
    o2.z = __shfl_xor(o.z, 32, 64);
    o2.w = __shfl_xor(o.w, 32, 64);
    float mn = fmaxf(m, m2);
    float s1 = __expf(m - mn), s2 = __expf(m2 - mn);
    den = den * s1 + den2 * s2;
    float inv = 1.f / (den + 1e-16f);
    if (half == 0) {
        float4 bv = *(const float4*)(b1 + ch);
        float4 res;
        res.x = fmaxf((o.x * s1 + o2.x * s2) * inv + bv.x, 0.f);
        res.y = fmaxf((o.y * s1 + o2.y * s2) * inv + bv.y, 0.f);
        res.z = fmaxf((o.z * s1 + o2.z * s2) * inv + bv.z, 0.f);
        res.w = fmaxf((o.w * s1 + o2.w * s2) * inv + bv.w, 0.f);
        *(float4*)(h1 + (size_t)n * 128 + ch) = res;
    }
}

// ------- fused GAT layer 2 (H=2, C=64, mean) + classifier tail --------------------
// tail v2: lane = (colgroup ln&15 -> 4 cols, jgroup ln>>4 -> K-rows j%4), float4
// weight loads, butterfly combine; LN in registers (only 4 gelu chains live/lane)
__global__ __launch_bounds__(256) void fused2cls(const int* __restrict__ base,
                                                 const int2* __restrict__ se,
                                                 const float* __restrict__ xl,
                                                 const float* __restrict__ xr,
                                                 const float* __restrict__ w2e,
                                                 const float* __restrict__ att2,
                                                 const float* __restrict__ b2,
                                                 const float* __restrict__ wc,
                                                 const float* __restrict__ bc,
                                                 const float* __restrict__ lng,
                                                 const float* __restrict__ lnb,
                                                 const float* __restrict__ wrr,
                                                 const float* __restrict__ brr,
                                                 const float* __restrict__ lrg,
                                                 const float* __restrict__ lrb,
                                                 float* __restrict__ out) {
    __shared__ float rowH[4][64];
    __shared__ float rowB[4][64];
    int t = threadIdx.x;
    int wv = t >> 6, ln = t & 63;
    int half = ln >> 5, sub = ln & 31;
    int n = blockIdx.x * 4 + wv;
    int ch = sub * 4;
    float4 xrv = *(const float4*)(xr + (size_t)n * 128 + ch);
    float4 wev = *(const float4*)(w2e + ch);
    float4 atv = *(const float4*)(att2 + ch);
    int i0 = base[n], i1 = base[n + 1];
    float m = -1e30f, den = 0.f;
    float4 o = make_float4(0.f, 0.f, 0.f, 0.f);
    int i = i0 + half;
    if (i < i1) {
        int2 r = se[i];
        float4 xv = *(const float4*)(xl + (size_t)r.x * 128 + ch);
        float a = __int_as_float(r.y);
        for (i += 2; i < i1; i += 2) {
            int2 rn = se[i];
            float4 nxv = *(const float4*)(xl + (size_t)rn.x * 128 + ch);
            float na = __int_as_float(rn.y);
            float part = lrelu(fmaf(a, wev.x, xv.x + xrv.x)) * atv.x
                       + lrelu(fmaf(a, wev.y, xv.y + xrv.y)) * atv.y
                       + lrelu(fmaf(a, wev.z, xv.z + xrv.z)) * atv.z
                       + lrelu(fmaf(a, wev.w, xv.w + xrv.w)) * atv.w;
            part += __shfl_xor(part, 1, 64);
            part += __shfl_xor(part, 2, 64);
            part += __shfl_xor(part, 4, 64);
            part += __shfl_xor(part, 8, 64);
            float mn = fmaxf(m, part);
            float sc = __expf(m - mn);
            float p  = __expf(part - mn);
            den = den * sc + p;
            o.x = o.x * sc + p * xv.x;
            o.y = o.y * sc + p * xv.y;
            o.z = o.z * sc + p * xv.z;
            o.w = o.w * sc + p * xv.w;
            m = mn;
            xv = nxv; a = na;
        }
        float part = lrelu(fmaf(a, wev.x, xv.x + xrv.x)) * atv.x
                   + lrelu(fmaf(a, wev.y, xv.y + xrv.y)) * atv.y
                   + lrelu(fmaf(a, wev.z, xv.z + xrv.z)) * atv.z
                   + lrelu(fmaf(a, wev.w, xv.w + xrv.w)) * atv.w;
        part += __shfl_xor(part, 1, 64);
        part += __shfl_xor(part, 2, 64);
        part += __shfl_xor(part, 4, 64);
        part += __shfl_xor(part, 8, 64);
        float mn = fmaxf(m, part);
        float sc = __expf(m - mn);
        float p  = __expf(part - mn);
        den = den * sc + p;
        o.x = o.x * sc + p * xv.x;
        o.y = o.y * sc + p * xv.y;
        o.z = o.z * sc + p * xv.z;
        o.w = o.w * sc + p * xv.w;
        m = mn;
    }
    float m2   = __shfl_xor(m, 32, 64);
    float den2 = __shfl_xor(den, 32, 64);
    float4 o2;
    o2.x = __shfl_xor(o.x, 32, 64);
    o2.y = __shfl_xor(o.y, 32, 64);
    o2.z = __shfl_xor(o.z, 32, 64);
    o2.w = __shfl_xor(o.w, 32, 64);
    float mn = fmaxf(m, m2);
    float s1 = __expf(m - mn), s2 = __expf(m2 - mn);
    den = den * s1 + den2 * s2;
    float inv = 1.f / (den + 1e-16f);
    float4 v;
    v.x = (o.x * s1 + o2.x * s2) * inv;
    v.y = (o.y * s1 + o2.y * s2) * inv;
    v.z = (o.z * s1 + o2.z * s2) * inv;
    v.w = (o.w * s1 + o2.w * s2) * inv;
    float4 u;
    u.x = __shfl_xor(v.x, 16, 64);
    u.y = __shfl_xor(v.y, 16, 64);
    u.z = __shfl_xor(v.z, 16, 64);
    u.w = __shfl_xor(v.w, 16, 64);
    if (half == 0 && sub < 16) {
        float4 bv = *(const float4*)(b2 + ch);
        float4 res;
        res.x = fmaxf(0.5f * (v.x + u.x) + bv.x, 0.f);
        res.y = fmaxf(0.5f * (v.y + u.y) + bv.y, 0.f);
        res.z = fmaxf(0.5f * (v.z + u.z) + bv.z, 0.f);
        res.w = fmaxf(0.5f * (v.w + u.w) + bv.w, 0.f);
        *(float4*)(&rowH[wv][ch]) = res;
    }
    __syncthreads();
    // ---- classifier tail v2 ----
    int cg16 = ln & 15, jg = ln >> 4;
    int cc = cg16 * 4;
    // matvec1: y = rowH @ wc + bc
    float4 acc = make_float4(0.f, 0.f, 0.f, 0.f);
    for (int jb = 0; jb < 64; jb += 4) {
        int j = jb + jg;
        float hv = rowH[wv][j];
        float4 w4 = *(const float4*)(wc + (size_t)j * 64 + cc);
        acc.x = fmaf(hv, w4.x, acc.x);
        acc.y = fmaf(hv, w4.y, acc.y);
        acc.z = fmaf(hv, w4.z, acc.z);
        acc.w = fmaf(hv, w4.w, acc.w);
    }
    acc.x += __shfl_xor(acc.x, 16, 64); acc.x += __shfl_xor(acc.x, 32, 64);
    acc.y += __shfl_xor(acc.y, 16, 64); acc.y += __shfl_xor(acc.y, 32, 64);
    acc.z += __shfl_xor(acc.z, 16, 64); acc.z += __shfl_xor(acc.z, 32, 64);
    acc.w += __shfl_xor(acc.w, 16, 64); acc.w += __shfl_xor(acc.w, 32, 64);
    float4 bv1 = *(const float4*)(bc + cc);
    acc.x += bv1.x; acc.y += bv1.y; acc.z += bv1.z; acc.w += bv1.w;
    // LN1 + GELU (16-lane-group butterfly on sum / sumsq)
    float ssum = acc.x + acc.y + acc.z + acc.w;
    float ssq  = acc.x * acc.x + acc.y * acc.y + acc.z * acc.z + acc.w * acc.w;
    #pragma unroll
    for (int d = 1; d < 16; d <<= 1) {
        ssum += __shfl_xor(ssum, d, 64);
        ssq  += __shfl_xor(ssq, d, 64);
    }
    float mu = ssum * (1.f / 64.f);
    float var = ssq * (1.f / 64.f) - mu * mu;
    float rstd = rsqrtf(var + 1e-5f);
    float4 lngv = *(const float4*)(lng + cc);
    float4 lnbv = *(const float4*)(lnb + cc);
    float4 g1;
    g1.x = gelu_exact((acc.x - mu) * rstd * lngv.x + lnbv.x);
    g1.y = gelu_exact((acc.y - mu) * rstd * lngv.y + lnbv.y);
    g1.z = gelu_exact((acc.z - mu) * rstd * lngv.z + lnbv.z);
    g1.w = gelu_exact((acc.w - mu) * rstd * lngv.w + lnbv.w);
    if (jg == 0) *(float4*)(&rowB[wv][cc]) = g1;
    __syncthreads();
    // matvec2: y = rowB @ wr + br
    float4 acc2 = make_float4(0.f, 0.f, 0.f, 0.f);
    for (int jb = 0; jb < 64; jb += 4) {
        int j = jb + jg;
        float hv = rowB[wv][j];
        float4 w4 = *(const float4*)(wrr + (size_t)j * 64 + cc);
        acc2.x = fmaf(hv, w4.x, acc2.x);
        acc2.y = fmaf(hv, w4.y, acc2.y);
        acc2.z = fmaf(hv, w4.z, acc2.z);
        acc2.w = fmaf(hv, w4.w, acc2.w);
    }
    acc2.x += __shfl_xor(acc2.x, 16, 64); acc2.x += __shfl_xor(acc2.x, 32, 64);
    acc2.y += __shfl_xor(acc2.y, 16, 64); acc2.y += __shfl_xor(acc2.y, 32, 64);
    acc2.z += __shfl_xor(acc2.z, 16, 64); acc2.z += __shfl_xor(acc2.z, 32, 64);
    acc2.w += __shfl_xor(acc2.w, 16, 64); acc2.w += __shfl_xor(acc2.w, 32, 64);
    float4 bv2 = *(const float4*)(brr + cc);
    acc2.x += bv2.x; acc2.y += bv2.y; acc2.z += bv2.z; acc2.w += bv2.w;
    float ssum2 = acc2.x + acc2.y + acc2.z + acc2.w;
    float ssq2  = acc2.x * acc2.x + acc2.y * acc2.y + acc2.z * acc2.z + acc2.w * acc2.w;
    #pragma unroll
    for (int d = 1; d < 16; d <<= 1) {
        ssum2 += __shfl_xor(ssum2, d, 64);
        ssq2  += __shfl_xor(ssq2, d, 64);
    }
    float mu2 = ssum2 * (1.f / 64.f);
    float var2 = ssq2 * (1.f / 64.f) - mu2 * mu2;
    float rstd2 = rsqrtf(var2 + 1e-5f);
    if (jg == 0) {
        float4 lrgv = *(const float4*)(lrg + cc);
        float4 lrbv = *(const float4*)(lrb + cc);
        float4 res;
        res.x = g1.x + gelu_exact((acc2.x - mu2) * rstd2 * lrgv.x + lrbv.x);
        res.y = g1.y + gelu_exact((acc2.y - mu2) * rstd2 * lrgv.y + lrbv.y);
        res.z = g1.z + gelu_exact((acc2.z - mu2) * rstd2 * lrgv.z + lrbv.z);
        res.w = g1.w + gelu_exact((acc2.w - mu2) * rstd2 * lrgv.w + lrbv.w);
        *(float4*)(out + (size_t)n * 64 + cc) = res;
    }
}

extern "C" void kernel_launch(void* const* d_in, const int* in_sizes, int n_in,
                              void* d_out, int out_size, void* d_ws, size_t ws_size,
                              hipStream_t stream) {
    const float* x    = (const float*)d_in[0];
    const int*   ei   = (const int*)d_in[1];
    const float* ea   = (const float*)d_in[2];
    const float* w1l  = (const float*)d_in[3];
    const float* w1r  = (const float*)d_in[4];
    const float* w1e  = (const float*)d_in[5];
    const float* att1 = (const float*)d_in[6];
    const float* b1   = (const float*)d_in[7];
    const float* w2l  = (const float*)d_in[8];
    const float* w2r  = (const float*)d_in[9];
    const float* w2e  = (const float*)d_in[10];
    const float* att2 = (const float*)d_in[11];
    const float* b2   = (const float*)d_in[12];
    const float* wc   = (const float*)d_in[13];
    const float* bc   = (const float*)d_in[14];
    const float* lng  = (const float*)d_in[15];
    const float* lnb  = (const float*)d_in[16];
    const float* wr   = (const float*)d_in[17];
    const float* br   = (const float*)d_in[18];
    const float* lrg  = (const float*)d_in[19];
    const float* lrb  = (const float*)d_in[20];

    float* ws = (float*)d_ws;
    const size_t N128 = (size_t)NNODE * 128;
    float* xl = ws;
    float* xr = xl + N128;
    float* h1 = xr + N128;
    int2*  se      = (int2*)(h1 + N128);      // NEDGE (8B aligned)
    int*   deg     = (int*)(se + NEDGE);
    int*   partial = deg + NNODE;
    int*   base    = partial + NNODE;         // NNODE+1
    int*   cursor  = base + NNODE + 1;
    int*   bsum    = cursor + NNODE;          // 256
    int*   boff    = bsum + 256;              // 256

    const int EB  = NEDGE / 256;              // 3125
    const int NBX = (NNODE + 31) / 32;        // 1563
    const int NB4 = NNODE / 4;                // 12500

    // ---- CSR build (dst-sorted) ----
    fill_u32<<<NBLK, 256, 0, stream>>>((unsigned*)deg, 0u, NNODE);
    build_deg<<<EB, 256, 0, stream>>>(ei, deg);
    scan1<<<NBLK, 256, 0, stream>>>(deg, partial, bsum);
    scan2<<<1, 256, 0, stream>>>(bsum, boff);
    scan3<<<NBLK, 256, 0, stream>>>(partial, boff, base, cursor);
    scatter_edges<<<EB, 256, 0, stream>>>(ei, ea, cursor, se);

    // ---- layer 1 ----
    node_xform<64><<<NBX, 256, 0, stream>>>(x, w1l, w1r, xl, xr);
    fused1<<<NB4, 256, 0, stream>>>(base, se, xl, xr, w1e, att1, b1, h1);

    // ---- layer 2 + classifier ----
    node_xform<128><<<NBX, 256, 0, stream>>>(h1, w2l, w2r, xl, xr);
    fused2cls<<<NB4, 256, 0, stream>>>(base, se, xl, xr, w2e, att2, b2,
                                       wc, bc, lng, lnb, wr, br, lrg, lrb,
                                       (float*)d_out);
}

// Round 14
// 344.865 us; speedup vs baseline: 1.2521x; 1.0130x over previous
//
#include <hip/hip_runtime.h>
#include <math.h>

#define NNODE 50000
#define NEDGE 800000
#define NBLK 196   // ceil(50000/256)

__device__ __forceinline__ float wsum64(float v) {
    #pragma unroll
    for (int m = 32; m >= 1; m >>= 1) v += __shfl_xor(v, m, 64);
    return v;
}

__device__ __forceinline__ float gelu_exact(float x) {
    return 0.5f * x * (1.0f + erff(x * 0.70710678118654752f));
}

__device__ __forceinline__ float lrelu(float z) { return z > 0.f ? z : 0.2f * z; }

__device__ __forceinline__ float bcast(float v, int lane) {
    return __uint_as_float(__builtin_amdgcn_readlane(__float_as_uint(v), lane));
}

// ---------------- utility ----------------
__global__ void fill_u32(unsigned* __restrict__ p, unsigned v, int n) {
    int i = blockIdx.x * blockDim.x + threadIdx.x;
    if (i < n) p[i] = v;
}

// ---------------- CSR build ----------------
__global__ __launch_bounds__(256) void build_deg(const int* __restrict__ ei, int* __restrict__ deg) {
    int e = blockIdx.x * 256 + threadIdx.x;
    if (e >= NEDGE) return;
    atomicAdd(&deg[ei[NEDGE + e]], 1);
}

// three-phase parallel exclusive scan
__global__ __launch_bounds__(256) void scan1(const int* __restrict__ deg,
                                             int* __restrict__ partial,
                                             int* __restrict__ bsum) {
    __shared__ int tmp[256];
    int t = threadIdx.x;
    int gid = blockIdx.x * 256 + t;
    int v = (gid < NNODE) ? deg[gid] : 0;
    tmp[t] = v;
    __syncthreads();
    #pragma unroll
    for (int off = 1; off < 256; off <<= 1) {
        int u = (t >= off) ? tmp[t - off] : 0;
        __syncthreads();
        tmp[t] += u;
        __syncthreads();
    }
    if (gid < NNODE) partial[gid] = tmp[t] - v;   // exclusive
    if (t == 255) bsum[blockIdx.x] = tmp[255];
}

__global__ __launch_bounds__(256) void scan2(int* __restrict__ bsum, int* __restrict__ boff) {
    __shared__ int tmp[256];
    int t = threadIdx.x;
    int v = (t < NBLK) ? bsum[t] : 0;
    tmp[t] = v;
    __syncthreads();
    #pragma unroll
    for (int off = 1; off < 256; off <<= 1) {
        int u = (t >= off) ? tmp[t - off] : 0;
        __syncthreads();
        tmp[t] += u;
        __syncthreads();
    }
    if (t < NBLK) boff[t] = tmp[t] - v;      // exclusive
}

__global__ __launch_bounds__(256) void scan3(const int* __restrict__ partial,
                                             const int* __restrict__ boff,
                                             int* __restrict__ base,
                                             int* __restrict__ cursor) {
    int gid = blockIdx.x * 256 + threadIdx.x;
    if (gid < NNODE) {
        int b = partial[gid] + boff[blockIdx.x];
        base[gid] = b;
        cursor[gid] = b;
    }
    if (gid == 0) base[NNODE] = NEDGE;
}

__global__ __launch_bounds__(256) void scatter_edges(const int* __restrict__ ei,
                                                     const float* __restrict__ ea,
                                                     int* __restrict__ cursor,
                                                     int2* __restrict__ se) {
    int e = blockIdx.x * 256 + threadIdx.x;
    if (e >= NEDGE) return;
    int d = ei[NEDGE + e];
    int i = atomicAdd(&cursor[d], 1);
    se[i] = make_int2(ei[e], __float_as_int(ea[e]));
}

// ---------------- node transform: 32 nodes/block, thread owns 4 cols x 8 nodes ----------
template<int K>
__global__ __launch_bounds__(256) void node_xform(const float* __restrict__ in,
                                                  const float* __restrict__ wl,
                                                  const float* __restrict__ wr,
                                                  float* __restrict__ xl,
                                                  float* __restrict__ xr) {
    __shared__ float xrow[32][K];
    int t = threadIdx.x;
    int n0 = blockIdx.x * 32;
    for (int idx = t; idx < 32 * (K / 4); idx += 256) {
        int row = idx / (K / 4), c4 = idx % (K / 4);
        float4 v = make_float4(0.f, 0.f, 0.f, 0.f);
        if (n0 + row < NNODE) v = ((const float4*)(in + (size_t)(n0 + row) * K))[c4];
        ((float4*)xrow[row])[c4] = v;
    }
    __syncthreads();
    int cg = t & 63, ns = t >> 6;
    const float* wsel = (cg < 32) ? wl : wr;
    float* osel = (cg < 32) ? xl : xr;
    int ccol = (cg & 31) * 4;
    const float* wp = wsel + ccol;
    const float* xbase = xrow[ns * 8];
    float4 acc[8];
    #pragma unroll
    for (int k = 0; k < 8; ++k) acc[k] = make_float4(0.f, 0.f, 0.f, 0.f);
    for (int i = 0; i < K; i += 4) {
        float4 w0 = *(const float4*)(wp + (size_t)(i + 0) * 128);
        float4 w1 = *(const float4*)(wp + (size_t)(i + 1) * 128);
        float4 w2 = *(const float4*)(wp + (size_t)(i + 2) * 128);
        float4 w3 = *(const float4*)(wp + (size_t)(i + 3) * 128);
        #pragma unroll
        for (int k = 0; k < 8; ++k) {
            float4 xv = *(const float4*)(xbase + (size_t)k * K + i);
            acc[k].x += xv.x * w0.x + xv.y * w1.x + xv.z * w2.x + xv.w * w3.x;
            acc[k].y += xv.x * w0.y + xv.y * w1.y + xv.z * w2.y + xv.w * w3.y;
            acc[k].z += xv.x * w0.z + xv.y * w1.z + xv.z * w2.z + xv.w * w3.z;
            acc[k].w += xv.x * w0.w + xv.y * w1.w + xv.z * w2.w + xv.w * w3.w;
        }
    }
    #pragma unroll
    for (int k = 0; k < 8; ++k) {
        int n = n0 + ns * 8 + k;
        if (n < NNODE) *(float4*)(osel + (size_t)n * 128 + ccol) = acc[k];
    }
}

// ---------------- fused online-softmax GAT layer 1 (H=8, C=16) ----------------
__global__ __launch_bounds__(256) void fused1(const int* __restrict__ base,
                                              const int2* __restrict__ se,
                                              const float* __restrict__ xl,
                                              const float* __restrict__ xr,
                                              const float* __restrict__ w1e,
                                              const float* __restrict__ att1,
                                              const float* __restrict__ b1,
                                              float* __restrict__ h1) {
    int t = threadIdx.x;
    int wv = t >> 6, ln = t & 63;
    int half = ln >> 5, sub = ln & 31;
    int n = blockIdx.x * 4 + wv;
    int ch = sub * 4;
    float4 xrv = *(const float4*)(xr + (size_t)n * 128 + ch);
    float4 wev = *(const float4*)(w1e + ch);
    float4 atv = *(const float4*)(att1 + ch);
    int i0 = base[n], i1 = base[n + 1];
    float m = -1e30f, den = 0.f;
    float4 o = make_float4(0.f, 0.f, 0.f, 0.f);
    int i = i0 + half;
    if (i < i1) {
        int2 r = se[i];
        float4 xv = *(const float4*)(xl + (size_t)r.x * 128 + ch);
        float a = __int_as_float(r.y);
        for (i += 2; i < i1; i += 2) {
            int2 rn = se[i];
            float4 nxv = *(const float4*)(xl + (size_t)rn.x * 128 + ch);
            float na = __int_as_float(rn.y);
            float part = lrelu(fmaf(a, wev.x, xv.x + xrv.x)) * atv.x
                       + lrelu(fmaf(a, wev.y, xv.y + xrv.y)) * atv.y
                       + lrelu(fmaf(a, wev.z, xv.z + xrv.z)) * atv.z
                       + lrelu(fmaf(a, wev.w, xv.w + xrv.w)) * atv.w;
            part += __shfl_xor(part, 1, 64);
            part += __shfl_xor(part, 2, 64);
            float mn = fmaxf(m, part);
            float sc = __expf(m - mn);
            float p  = __expf(part - mn);
            den = den * sc + p;
            o.x = o.x * sc + p * xv.x;
            o.y = o.y * sc + p * xv.y;
            o.z = o.z * sc + p * xv.z;
            o.w = o.w * sc + p * xv.w;
            m = mn;
            xv = nxv; a = na;
        }
        float part = lrelu(fmaf(a, wev.x, xv.x + xrv.x)) * atv.x
                   + lrelu(fmaf(a, wev.y, xv.y + xrv.y)) * atv.y
                   + lrelu(fmaf(a, wev.z, xv.z + xrv.z)) * atv.z
                   + lrelu(fmaf(a, wev.w, xv.w + xrv.w)) * atv.w;
        part += __shfl_xor(part, 1, 64);
        part += __shfl_xor(part, 2, 64);
        float mn = fmaxf(m, part);
        float sc = __expf(m - mn);
        float p  = __expf(part - mn);
        den = den * sc + p;
        o.x = o.x * sc + p * xv.x;
        o.y = o.y * sc + p * xv.y;
        o.z = o.z * sc + p * xv.z;
        o.w = o.w * sc + p * xv.w;
        m = mn;
    }
    float m2   = __shfl_xor(m, 32, 64);
    float den2 = __shfl_xor(den, 32, 64);
    float4 o2;
    o2.x = __shfl_xor(o.x, 32, 64);
    o2.y = __shfl_xor(o.y, 32, 64);
    o2.z = __shfl_xor(o.z, 32, 64);
    o2.w = __shfl_xor(o.w, 32, 64);
    float mn = fmaxf(m, m2);
    float s1 = __expf(m - mn), s2 = __expf(m2 - mn);
    den = den * s1 + den2 * s2;
    float inv = 1.f / (den + 1e-16f);
    if (half == 0) {
        float4 bv = *(const float4*)(b1 + ch);
        float4 res;
        res.x = fmaxf((o.x * s1 + o2.x * s2) * inv + bv.x, 0.f);
        res.y = fmaxf((o.y * s1 + o2.y * s2) * inv + bv.y, 0.f);
        res.z = fmaxf((o.z * s1 + o2.z * s2) * inv + bv.z, 0.f);
        res.w = fmaxf((o.w * s1 + o2.w * s2) * inv + bv.w, 0.f);
        *(float4*)(h1 + (size_t)n * 128 + ch) = res;
    }
}

// ---------------- fused online-softmax GAT layer 2 (H=2, C=64, mean) ----------------
__global__ __launch_bounds__(256) void fused2(const int* __restrict__ base,
                                              const int2* __restrict__ se,
                                              const float* __restrict__ xl,
                                              const float* __restrict__ xr,
                                              const float* __restrict__ w2e,
                                              const float* __restrict__ att2,
                                              const float* __restrict__ b2,
                                              float* __restrict__ h2) {
    int t = threadIdx.x;
    int wv = t >> 6, ln = t & 63;
    int half = ln >> 5, sub = ln & 31;
    int n = blockIdx.x * 4 + wv;
    int ch = sub * 4;
    float4 xrv = *(const float4*)(xr + (size_t)n * 128 + ch);
    float4 wev = *(const float4*)(w2e + ch);
    float4 atv = *(const float4*)(att2 + ch);
    int i0 = base[n], i1 = base[n + 1];
    float m = -1e30f, den = 0.f;
    float4 o = make_float4(0.f, 0.f, 0.f, 0.f);
    int i = i0 + half;
    if (i < i1) {
        int2 r = se[i];
        float4 xv = *(const float4*)(xl + (size_t)r.x * 128 + ch);
        float a = __int_as_float(r.y);
        for (i += 2; i < i1; i += 2) {
            int2 rn = se[i];
            float4 nxv = *(const float4*)(xl + (size_t)rn.x * 128 + ch);
            float na = __int_as_float(rn.y);
            float part = lrelu(fmaf(a, wev.x, xv.x + xrv.x)) * atv.x
                       + lrelu(fmaf(a, wev.y, xv.y + xrv.y)) * atv.y
                       + lrelu(fmaf(a, wev.z, xv.z + xrv.z)) * atv.z
                       + lrelu(fmaf(a, wev.w, xv.w + xrv.w)) * atv.w;
            part += __shfl_xor(part, 1, 64);
            part += __shfl_xor(part, 2, 64);
            part += __shfl_xor(part, 4, 64);
            part += __shfl_xor(part, 8, 64);
            float mn = fmaxf(m, part);
            float sc = __expf(m - mn);
            float p  = __expf(part - mn);
            den = den * sc + p;
            o.x = o.x * sc + p * xv.x;
            o.y = o.y * sc + p * xv.y;
            o.z = o.z * sc + p * xv.z;
            o.w = o.w * sc + p * xv.w;
            m = mn;
            xv = nxv; a = na;
        }
        float part = lrelu(fmaf(a, wev.x, xv.x + xrv.x)) * atv.x
                   + lrelu(fmaf(a, wev.y, xv.y + xrv.y)) * atv.y
                   + lrelu(fmaf(a, wev.z, xv.z + xrv.z)) * atv.z
                   + lrelu(fmaf(a, wev.w, xv.w + xrv.w)) * atv.w;
        part += __shfl_xor(part, 1, 64);
        part += __shfl_xor(part, 2, 64);
        part += __shfl_xor(part, 4, 64);
        part += __shfl_xor(part, 8, 64);
        float mn = fmaxf(m, part);
        float sc = __expf(m - mn);
        float p  = __expf(part - mn);
        den = den * sc + p;
        o.x = o.x * sc + p * xv.x;
        o.y = o.y * sc + p * xv.y;
        o.z = o.z * sc + p * xv.z;
        o.w = o.w * sc + p * xv.w;
        m = mn;
    }
    float m2   = __shfl_xor(m, 32, 64);
    float den2 = __shfl_xor(den, 32, 64);
    float4 o2;
    o2.x = __shfl_xor(o.x, 32, 64);
    o2.y = __shfl_xor(o.y, 32, 64);
    o2.z = __shfl_xor(o.z, 32, 64);
    o2.w = __shfl_xor(o.w, 32, 64);
    float mn = fmaxf(m, m2);
    float s1 = __expf(m - mn), s2 = __expf(m2 - mn);
    den = den * s1 + den2 * s2;
    float inv = 1.f / (den + 1e-16f);
    float4 v;
    v.x = (o.x * s1 + o2.x * s2) * inv;
    v.y = (o.y * s1 + o2.y * s2) * inv;
    v.z = (o.z * s1 + o2.z * s2) * inv;
    v.w = (o.w * s1 + o2.w * s2) * inv;
    float4 u;
    u.x = __shfl_xor(v.x, 16, 64);
    u.y = __shfl_xor(v.y, 16, 64);
    u.z = __shfl_xor(v.z, 16, 64);
    u.w = __shfl_xor(v.w, 16, 64);
    if (half == 0 && sub < 16) {
        float4 bv = *(const float4*)(b2 + ch);
        float4 res;
        res.x = fmaxf(0.5f * (v.x + u.x) + bv.x, 0.f);
        res.y = fmaxf(0.5f * (v.y + u.y) + bv.y, 0.f);
        res.z = fmaxf(0.5f * (v.z + u.z) + bv.z, 0.f);
        res.w = fmaxf(0.5f * (v.w + u.w) + bv.w, 0.f);
        *(float4*)(h2 + (size_t)n * 64 + ch) = res;
    }
}

// ------- classifier v5: weight-stationary in registers, grid-stride waves --------
// lane ln holds wc[:,ln] and wr[:,ln] (128 VGPRs, literal-indexed); h broadcast
// via v_readlane; zero weight memory traffic inside the node loop.
__global__ __launch_bounds__(256) void classifier_reg(const float* __restrict__ h2,
                                                      const float* __restrict__ wc,
                                                      const float* __restrict__ bc,
                                                      const float* __restrict__ lng,
                                                      const float* __restrict__ lnb,
                                                      const float* __restrict__ wrr,
                                                      const float* __restrict__ brr,
                                                      const float* __restrict__ lrg,
                                                      const float* __restrict__ lrb,
                                                      float* __restrict__ out,
                                                      int nwaves_total) {
    int t = threadIdx.x;
    int ln = t & 63;
    int wid = (blockIdx.x * 256 + t) >> 6;
    float wcr[64], wrg[64];
    #pragma unroll
    for (int j = 0; j < 64; ++j) wcr[j] = wc[(size_t)j * 64 + ln];
    #pragma unroll
    for (int j = 0; j < 64; ++j) wrg[j] = wrr[(size_t)j * 64 + ln];
    float bcv = bc[ln], lngv = lng[ln], lnbv = lnb[ln];
    float brv = brr[ln], lrgv = lrg[ln], lrbv = lrb[ln];
    for (int n = wid; n < NNODE; n += nwaves_total) {
        float h = h2[(size_t)n * 64 + ln];
        // matvec1: acc[ln] = sum_j h[j] * wc[j][ln]  (4 independent chains)
        float a0 = bcv, a1 = 0.f, a2 = 0.f, a3 = 0.f;
        #pragma unroll
        for (int j = 0; j < 64; j += 4) {
            a0 = fmaf(bcast(h, j + 0), wcr[j + 0], a0);
            a1 = fmaf(bcast(h, j + 1), wcr[j + 1], a1);
            a2 = fmaf(bcast(h, j + 2), wcr[j + 2], a2);
            a3 = fmaf(bcast(h, j + 3), wcr[j + 3], a3);
        }
        float acc = (a0 + a1) + (a2 + a3);
        float mu = wsum64(acc) * (1.f / 64.f);
        float dv = acc - mu;
        float var = wsum64(dv * dv) * (1.f / 64.f);
        float g1 = gelu_exact(dv * rsqrtf(var + 1e-5f) * lngv + lnbv);
        // matvec2: acc2[ln] = sum_j g1[j] * wr[j][ln]
        float b0 = brv, b1v = 0.f, b2v = 0.f, b3v = 0.f;
        #pragma unroll
        for (int j = 0; j < 64; j += 4) {
            b0  = fmaf(bcast(g1, j + 0), wrg[j + 0], b0);
            b1v = fmaf(bcast(g1, j + 1), wrg[j + 1], b1v);
            b2v = fmaf(bcast(g1, j + 2), wrg[j + 2], b2v);
            b3v = fmaf(bcast(g1, j + 3), wrg[j + 3], b3v);
        }
        float acc2 = (b0 + b1v) + (b2v + b3v);
        float mu2 = wsum64(acc2) * (1.f / 64.f);
        float dv2 = acc2 - mu2;
        float var2 = wsum64(dv2 * dv2) * (1.f / 64.f);
        float g2 = gelu_exact(dv2 * rsqrtf(var2 + 1e-5f) * lrgv + lrbv);
        out[(size_t)n * 64 + ln] = g1 + g2;
    }
}

extern "C" void kernel_launch(void* const* d_in, const int* in_sizes, int n_in,
                              void* d_out, int out_size, void* d_ws, size_t ws_size,
                              hipStream_t stream) {
    const float* x    = (const float*)d_in[0];
    const int*   ei   = (const int*)d_in[1];
    const float* ea   = (const float*)d_in[2];
    const float* w1l  = (const float*)d_in[3];
    const float* w1r  = (const float*)d_in[4];
    const float* w1e  = (const float*)d_in[5];
    const float* att1 = (const float*)d_in[6];
    const float* b1   = (const float*)d_in[7];
    const float* w2l  = (const float*)d_in[8];
    const float* w2r  = (const float*)d_in[9];
    const float* w2e  = (const float*)d_in[10];
    const float* att2 = (const float*)d_in[11];
    const float* b2   = (const float*)d_in[12];
    const float* wc   = (const float*)d_in[13];
    const float* bc   = (const float*)d_in[14];
    const float* lng  = (const float*)d_in[15];
    const float* lnb  = (const float*)d_in[16];
    const float* wr   = (const float*)d_in[17];
    const float* br   = (const float*)d_in[18];
    const float* lrg  = (const float*)d_in[19];
    const float* lrb  = (const float*)d_in[20];

    float* ws = (float*)d_ws;
    const size_t N128 = (size_t)NNODE * 128;
    float* xl = ws;
    float* xr = xl + N128;
    float* h1 = xr + N128;
    float* h2 = h1 + N128;                    // N*64
    int2*  se      = (int2*)(h2 + (size_t)NNODE * 64);   // NEDGE (8B aligned)
    int*   deg     = (int*)(se + NEDGE);
    int*   partial = deg + NNODE;
    int*   base    = partial + NNODE;         // NNODE+1
    int*   cursor  = base + NNODE + 1;
    int*   bsum    = cursor + NNODE;          // 256
    int*   boff    = bsum + 256;              // 256

    const int EB  = NEDGE / 256;              // 3125
    const int NBX = (NNODE + 31) / 32;        // 1563
    const int NB4 = NNODE / 4;                // 12500
    const int CBLK = 640;                     // classifier blocks (2560 waves)

    // ---- CSR build (dst-sorted) ----
    fill_u32<<<NBLK, 256, 0, stream>>>((unsigned*)deg, 0u, NNODE);
    build_deg<<<EB, 256, 0, stream>>>(ei, deg);
    scan1<<<NBLK, 256, 0, stream>>>(deg, partial, bsum);
    scan2<<<1, 256, 0, stream>>>(bsum, boff);
    scan3<<<NBLK, 256, 0, stream>>>(partial, boff, base, cursor);
    scatter_edges<<<EB, 256, 0, stream>>>(ei, ea, cursor, se);

    // ---- layer 1 ----
    node_xform<64><<<NBX, 256, 0, stream>>>(x, w1l, w1r, xl, xr);
    fused1<<<NB4, 256, 0, stream>>>(base, se, xl, xr, w1e, att1, b1, h1);

    // ---- layer 2 ----
    node_xform<128><<<NBX, 256, 0, stream>>>(h1, w2l, w2r, xl, xr);
    fused2<<<NB4, 256, 0, stream>>>(base, se, xl, xr, w2e, att2, b2, h2);

    // ---- classifier (weight-stationary registers, grid-stride) ----
    classifier_reg<<<CBLK, 256, 0, stream>>>(h2, wc, bc, lng, lnb, wr, br, lrg, lrb,
                                             (float*)d_out, CBLK * 4);
}